// Round 1
// baseline (149.491 us; speedup 1.0000x reference)
//
#include <hip/hip_runtime.h>
#include <hip/hip_bf16.h>

// Problem constants (match reference)
#define BB      16
#define LL      128
#define LOCM    1024
#define EMBD    16
// SU=100, SL=0, TU=24, TL=0

// out[b,l,j,e] = C1[b,l,e] + mat2[traj_loc[b,l]-1, j] * C2[b,l,e]
//   C1[e] = esl[m][e] + etl[m][e] + dt * (etu[m][e]-etl[m][e]) / 24
//   C2[e] = valid ? (esu[m][e]-esl[m][e]) / 100 : 0
// valid = l < traj_len[b]; m = valid?1:0; dt = vec[b,l] (NOT masked in ref).
// Write-BW-bound: 128 MiB out. One block per (b,l): stage mat2 row (4 KiB)
// in LDS, stream 64 KiB of coalesced float4 stores.

__global__ __launch_bounds__(256) void embed_kernel(
    const int*   __restrict__ traj_loc,
    const float* __restrict__ mat2,
    const float* __restrict__ vec,
    const int*   __restrict__ traj_len,
    const float* __restrict__ emb_su,
    const float* __restrict__ emb_sl,
    const float* __restrict__ emb_tu,
    const float* __restrict__ emb_tl,
    float*       __restrict__ out)
{
    __shared__ float row[LOCM];

    const int bl = blockIdx.x;          // 0 .. B*L-1
    const int b  = bl >> 7;             // bl / L
    const int l  = bl & (LL - 1);
    const int t  = threadIdx.x;

    const bool valid = l < traj_len[b];
    const int  m     = valid ? 1 : 0;
    const int  loc   = traj_loc[bl] - 1;          // [0, LOCM)
    const float dt   = vec[bl];

    // Stage mat2 row into LDS: 256 threads x float4 = 1024 floats, coalesced.
    const float4* src = (const float4*)(mat2 + (size_t)loc * LOCM);
    ((float4*)row)[t] = src[t];

    // Per-thread C1/C2 over 4 consecutive emb elements; e4 lane fixed = t&3.
    const int e0 = (t & 3) * 4;
    const float inv_t = 1.0f / 24.0f;
    const float inv_s = valid ? (1.0f / 100.0f) : 0.0f;

    float c1[4], c2[4];
    {
        const float* psl = emb_sl + m * EMBD + e0;
        const float* psu = emb_su + m * EMBD + e0;
        const float* ptl = emb_tl + m * EMBD + e0;
        const float* ptu = emb_tu + m * EMBD + e0;
#pragma unroll
        for (int k = 0; k < 4; ++k) {
            const float a_sl = psl[k];
            const float a_su = psu[k];
            const float a_tl = ptl[k];
            const float a_tu = ptu[k];
            c1[k] = a_sl + a_tl + dt * (a_tu - a_tl) * inv_t;
            c2[k] = (a_su - a_sl) * inv_s;
        }
    }

    __syncthreads();

    // Each thread: 16 float4 stores at flat-f4 index t + 256*i (coalesced).
    // j = (t>>2) + 64*i ; LDS read row[j] is a 4-lane broadcast, 16 banks.
    float4* dst = (float4*)(out + (size_t)bl * (LOCM * EMBD));
    const int jb = t >> 2;
#pragma unroll
    for (int i = 0; i < 16; ++i) {
        const float ds = row[jb + 64 * i];
        float4 v;
        v.x = fmaf(ds, c2[0], c1[0]);
        v.y = fmaf(ds, c2[1], c1[1]);
        v.z = fmaf(ds, c2[2], c1[2]);
        v.w = fmaf(ds, c2[3], c1[3]);
        dst[t + 256 * i] = v;
    }
}

extern "C" void kernel_launch(void* const* d_in, const int* in_sizes, int n_in,
                              void* d_out, int out_size, void* d_ws, size_t ws_size,
                              hipStream_t stream)
{
    const int*   traj_loc = (const int*)  d_in[0];
    const float* mat2     = (const float*)d_in[1];
    const float* vec      = (const float*)d_in[2];
    const int*   traj_len = (const int*)  d_in[3];
    const float* emb_su_w = (const float*)d_in[4];
    const float* emb_sl_w = (const float*)d_in[5];
    const float* emb_tu_w = (const float*)d_in[6];
    const float* emb_tl_w = (const float*)d_in[7];
    float* out = (float*)d_out;

    dim3 grid(BB * LL);   // 2048 blocks, one per (b,l)
    dim3 block(256);
    embed_kernel<<<grid, block, 0, stream>>>(
        traj_loc, mat2, vec, traj_len,
        emb_su_w, emb_sl_w, emb_tu_w, emb_tl_w, out);
}